// Round 16
// baseline (417.778 us; speedup 1.0000x reference)
//
#include <hip/hip_runtime.h>
#include <hip/hip_fp16.h>
#include <math.h>

#define N_GRAPHS 512
#define CAP 5120          // bucket capacity: mean 4096, sigma 64
#define TILE_A 4096       // edges per phase-A workgroup (16/thread)

static inline size_t align_up(size_t v, size_t a) { return (v + a - 1) / a * a; }

// ---- init: bucket cursors + zero scalar pooled + done counter ---------------
__global__ void k_init(int* __restrict__ cursor, float* __restrict__ pooledS,
                       int* __restrict__ done, int nb) {
    int i = blockIdx.x * blockDim.x + threadIdx.x;
    if (i < nb) cursor[i] = i * CAP;
    if (i < N_GRAPHS) pooledS[i] = 0.f;
    if (i == 0) *done = 0;
}

// ---- Phase A: partition edges into dst-range buckets ------------------------
__global__ void k_bucketA(const int* __restrict__ src, const int* __restrict__ dst,
                          int* __restrict__ cursor, int* __restrict__ bucketBuf,
                          int ne, int nb) {
    __shared__ int hist[512];
    __shared__ int base[512];
    for (int i = threadIdx.x; i < nb; i += 256) hist[i] = 0;
    __syncthreads();
    int t0 = blockIdx.x * TILE_A + threadIdx.x;
    int s[16], d[16];
#pragma unroll
    for (int k = 0; k < 16; ++k) {
        int e = t0 + k * 256;
        if (e < ne) {
            s[k] = __builtin_nontemporal_load(src + e);
            d[k] = __builtin_nontemporal_load(dst + e);
        } else { s[k] = 0; d[k] = -1; }
    }
#pragma unroll
    for (int k = 0; k < 16; ++k)
        if (d[k] >= 0) atomicAdd(&hist[d[k] >> 8], 1);
    __syncthreads();
    for (int i = threadIdx.x; i < nb; i += 256)
        base[i] = (hist[i] > 0) ? atomicAdd(&cursor[i], hist[i]) : 0;
    __syncthreads();
#pragma unroll
    for (int k = 0; k < 16; ++k)
        if (d[k] >= 0) {
            int b = d[k] >> 8;
            int slot = atomicAdd(&base[b], 1);
            int lim = b * CAP + (CAP - 1);
            if (slot > lim) slot = lim;   // overflow guard (never expected)
            bucketBuf[slot] = (s[k] << 8) | (d[k] & 255);
        }
}

// ---- Phase B: counting sort -> csr + pk + dinv + prescaled fp16 x [n][16] ---
__global__ void k_bucketB(const int* __restrict__ cursor, const int* __restrict__ bucketBuf,
                          const float* __restrict__ x,
                          int* __restrict__ csr, unsigned* __restrict__ pk,
                          float* __restrict__ dinv, __half* __restrict__ xh, int n) {
    int b = blockIdx.x;
    int beg = b * CAP;
    int cnt = cursor[b] - beg;
    if (cnt > CAP) cnt = CAP;
    __shared__ int hist[256];
    __shared__ int scan[256];
    hist[threadIdx.x] = 0;
    __syncthreads();
    for (int j = threadIdx.x; j < cnt; j += 256)
        atomicAdd(&hist[__builtin_nontemporal_load(bucketBuf + beg + j) & 255], 1);
    __syncthreads();
    int v = hist[threadIdx.x];
    scan[threadIdx.x] = v;
    __syncthreads();
    for (int off = 1; off < 256; off <<= 1) {
        int t = (threadIdx.x >= off) ? scan[threadIdx.x - off] : 0;
        __syncthreads();
        scan[threadIdx.x] += t;
        __syncthreads();
    }
    int excl = scan[threadIdx.x] - v;
    int node = (b << 8) + threadIdx.x;
    if (node < n) {
        pk[node] = (unsigned)(beg + excl) | ((unsigned)v << 22);
        float dd = (float)v + 1.0f;
        float dv = 1.0f / sqrtf(dd);
        dinv[node] = dv;
        // fused pad: xh[node] = dv * x[node], 10 feats zero-padded to 16 (fp16)
        const float* row = x + (size_t)node * 10;
        float vals[16];
#pragma unroll
        for (int k = 0; k < 10; ++k) vals[k] = row[k] * dv;
#pragma unroll
        for (int k = 10; k < 16; ++k) vals[k] = 0.f;
        __half2 out[8];
#pragma unroll
        for (int i = 0; i < 8; ++i) out[i] = __floats2half2_rn(vals[2 * i], vals[2 * i + 1]);
        *(float4*)(xh + (size_t)node * 16)     = *(float4*)(out);
        *(float4*)(xh + (size_t)node * 16 + 8) = *(float4*)(out + 4);
    }
    __syncthreads();
    hist[threadIdx.x] = excl;   // reuse as scatter cursor
    __syncthreads();
    for (int j = threadIdx.x; j < cnt; j += 256) {
        int pkk = __builtin_nontemporal_load(bucketBuf + beg + j);
        int slot = atomicAdd(&hist[pkk & 255], 1);
        csr[beg + slot] = pkk >> 8;
    }
}

// 8 fp16 feats -> add into a0..a7
#define CVT8ADD(qq) do { \
    const __half2* hp_ = (const __half2*)&(qq); \
    float2 f0_ = __half22float2(hp_[0]); \
    float2 f1_ = __half22float2(hp_[1]); \
    float2 f2_ = __half22float2(hp_[2]); \
    float2 f3_ = __half22float2(hp_[3]); \
    a0 += f0_.x; a1 += f0_.y; a2 += f1_.x; a3 += f1_.y; \
    a4 += f2_.x; a5 += f2_.y; a6 += f3_.x; a7 += f3_.y; } while (0)

#define RED8(mask) do { \
    a0 += __shfl_xor(a0, mask); a1 += __shfl_xor(a1, mask); \
    a2 += __shfl_xor(a2, mask); a3 += __shfl_xor(a3, mask); \
    a4 += __shfl_xor(a4, mask); a5 += __shfl_xor(a5, mask); \
    a6 += __shfl_xor(a6, mask); a7 += __shfl_xor(a7, mask); } while (0)

// 4-edge-unrolled gather loop over a table of 32 B fp16 rows
// lane layout: half = lane&1; edge-slot q = (lane>>1)&3; node slot = lane>>3
#define GATHER_LOOP16(tbl) do { \
    int j = beg + q; \
    for (; j + 12 < end; j += 16) { \
        int sA = __builtin_nontemporal_load(csr + j); \
        int sB = __builtin_nontemporal_load(csr + j + 4); \
        int sC = __builtin_nontemporal_load(csr + j + 8); \
        int sD = __builtin_nontemporal_load(csr + j + 12); \
        float4 qA = *(const float4*)((tbl) + (size_t)sA * 16 + half * 8); \
        float4 qB = *(const float4*)((tbl) + (size_t)sB * 16 + half * 8); \
        float4 qC = *(const float4*)((tbl) + (size_t)sC * 16 + half * 8); \
        float4 qD = *(const float4*)((tbl) + (size_t)sD * 16 + half * 8); \
        CVT8ADD(qA); CVT8ADD(qB); CVT8ADD(qC); CVT8ADD(qD); \
    } \
    for (; j < end; j += 4) { \
        int s = __builtin_nontemporal_load(csr + j); \
        float4 qq = *(const float4*)((tbl) + (size_t)s * 16 + half * 8); \
        CVT8ADD(qq); \
    } } while (0)

// ---- fused gather1 + MLP: mh = fp16(dinv * (relu(z@W1+b1)@W2))  [n][32] -----
// 64 nodes per 512-thread block; z only in LDS; x table fp16 [n][16] (3.2 MB).
__global__ void k_g1lin(const int* __restrict__ csr, const unsigned* __restrict__ pk,
                        const float* __restrict__ dinv, const __half* __restrict__ xh,
                        const float* __restrict__ W1, const float* __restrict__ b1,
                        const float* __restrict__ W2, __half* __restrict__ mh, int n) {
    __shared__ __align__(16) float W1s[640];
    __shared__ __align__(16) float W2s[2048];
    __shared__ __align__(16) float zt[64 * 17];
    __shared__ __align__(16) float hs[64 * 65];
    for (int i = threadIdx.x; i < 640; i += 512)  W1s[i] = W1[i];
    for (int i = threadIdx.x; i < 2048; i += 512) W2s[i] = W2[i];

    int half = threadIdx.x & 1;
    int q = (threadIdx.x >> 1) & 3;
    int slot = threadIdx.x >> 3;                 // 0..63
    int v = blockIdx.x * 64 + slot;
    bool valid = (v < n);
    float a0=0.f,a1=0.f,a2=0.f,a3=0.f,a4=0.f,a5=0.f,a6=0.f,a7=0.f;
    if (valid) {
        unsigned p = pk[v];
        int beg = (int)(p & 0x3FFFFFu), end = beg + (int)(p >> 22);
        GATHER_LOOP16(xh);
    }
    RED8(2); RED8(4);
    if (q == 0) {
        float o[8] = {0.f,0.f,0.f,0.f,0.f,0.f,0.f,0.f};
        if (valid) {
            float dv = dinv[v];
            float4 qs = *(const float4*)(xh + (size_t)v * 16 + half * 8);
            const __half2* sp = (const __half2*)&qs;
            float2 s0 = __half22float2(sp[0]), s1 = __half22float2(sp[1]);
            float2 s2 = __half22float2(sp[2]), s3 = __half22float2(sp[3]);
            o[0] = (a0 + s0.x) * dv; o[1] = (a1 + s0.y) * dv;
            o[2] = (a2 + s1.x) * dv; o[3] = (a3 + s1.y) * dv;
            o[4] = (a4 + s2.x) * dv; o[5] = (a5 + s2.y) * dv;
            o[6] = (a6 + s3.x) * dv; o[7] = (a7 + s3.y) * dv;
        }
        float* zr = zt + slot * 17 + half * 8;
#pragma unroll
        for (int i = 0; i < 8; ++i) zr[i] = o[i];
    }
    __syncthreads();
    // h1 phase: node = tid&63, w = tid>>6 computes 8 consecutive feats via
    // broadcast b128 W1 reads (all 64 lanes same address).
    {
        int node = threadIdx.x & 63, w = threadIdx.x >> 6;
        float zreg[10];
#pragma unroll
        for (int k = 0; k < 10; ++k) zreg[k] = zt[node * 17 + k];
        float acc[8];
        {
            float4 bva = *(const float4*)(b1 + w * 8);
            float4 bvb = *(const float4*)(b1 + w * 8 + 4);
            acc[0] = bva.x; acc[1] = bva.y; acc[2] = bva.z; acc[3] = bva.w;
            acc[4] = bvb.x; acc[5] = bvb.y; acc[6] = bvb.z; acc[7] = bvb.w;
        }
        const float4* W1v = (const float4*)W1s;
#pragma unroll
        for (int k = 0; k < 10; ++k) {
            float zk = zreg[k];
            float4 wa = W1v[k * 16 + w * 2];
            float4 wb = W1v[k * 16 + w * 2 + 1];
            acc[0] += zk * wa.x; acc[1] += zk * wa.y;
            acc[2] += zk * wa.z; acc[3] += zk * wa.w;
            acc[4] += zk * wb.x; acc[5] += zk * wb.y;
            acc[6] += zk * wb.z; acc[7] += zk * wb.w;
        }
        float* hr = hs + node * 65 + w * 8;
#pragma unroll
        for (int i = 0; i < 8; ++i) hr[i] = fmaxf(acc[i], 0.f);
    }
    __syncthreads();
    // m phase (register-blocked): node = tid>>3, 4 consecutive outputs og*4..+3.
    {
        int node = threadIdx.x >> 3, og = threadIdx.x & 7;
        int vv = blockIdx.x * 64 + node;
        if (vv < n) {
            float s0 = 0.f, s1 = 0.f, s2 = 0.f, s3 = 0.f;
            const float4* W2v = (const float4*)W2s;   // [f][32] -> f*8 float4s
            const float* hr = hs + node * 65;
#pragma unroll
            for (int f = 0; f < 64; ++f) {
                float hv = hr[f];
                float4 w4 = W2v[f * 8 + og];
                s0 += hv * w4.x; s1 += hv * w4.y;
                s2 += hv * w4.z; s3 += hv * w4.w;
            }
            float dv = dinv[vv];
            __half2 p0 = __floats2half2_rn(s0 * dv, s1 * dv);
            __half2 p1 = __floats2half2_rn(s2 * dv, s3 * dv);
            __half2* outp = (__half2*)(mh + (size_t)vv * 32 + og * 4);
            outp[0] = p0; outp[1] = p1;
        }
    }
}

// ---- gather2 single pass + relu + FC dot + scalar pool + fused final FC -----
// lane layout: quarter = lane&3; edge-slot q = (lane>>2)&1; node slot = lane>>3
__global__ void k_gath2(const int* __restrict__ csr, const unsigned* __restrict__ pk,
                        const float* __restrict__ dinv, const __half* __restrict__ mh,
                        const float* __restrict__ b2, const float* __restrict__ Wfc,
                        const int* __restrict__ batch, float* __restrict__ pooledS,
                        int* __restrict__ done, const float* __restrict__ bfc,
                        float* __restrict__ out, int n) {
    int quarter = threadIdx.x & 3;
    int q = (threadIdx.x >> 2) & 1;
    int v = blockIdx.x * 32 + (threadIdx.x >> 3);
    bool valid = (v < n);
    float a0=0.f,a1=0.f,a2=0.f,a3=0.f,a4=0.f,a5=0.f,a6=0.f,a7=0.f;
    int b = -1;
    if (valid) {
        unsigned p = pk[v];
        int beg = (int)(p & 0x3FFFFFu), end = beg + (int)(p >> 22);
        int j = beg + q;
        // 8-deep unroll: deg/2 edges per q-lane; 8 rows in flight per lane
        for (; j + 14 < end; j += 16) {
            int s0 = __builtin_nontemporal_load(csr + j);
            int s1 = __builtin_nontemporal_load(csr + j + 2);
            int s2 = __builtin_nontemporal_load(csr + j + 4);
            int s3 = __builtin_nontemporal_load(csr + j + 6);
            int s4 = __builtin_nontemporal_load(csr + j + 8);
            int s5 = __builtin_nontemporal_load(csr + j + 10);
            int s6 = __builtin_nontemporal_load(csr + j + 12);
            int s7 = __builtin_nontemporal_load(csr + j + 14);
            float4 q0 = *(const float4*)(mh + (size_t)s0 * 32 + quarter * 8);
            float4 q1 = *(const float4*)(mh + (size_t)s1 * 32 + quarter * 8);
            float4 q2 = *(const float4*)(mh + (size_t)s2 * 32 + quarter * 8);
            float4 q3 = *(const float4*)(mh + (size_t)s3 * 32 + quarter * 8);
            float4 q4 = *(const float4*)(mh + (size_t)s4 * 32 + quarter * 8);
            float4 q5 = *(const float4*)(mh + (size_t)s5 * 32 + quarter * 8);
            float4 q6 = *(const float4*)(mh + (size_t)s6 * 32 + quarter * 8);
            float4 q7 = *(const float4*)(mh + (size_t)s7 * 32 + quarter * 8);
            CVT8ADD(q0); CVT8ADD(q1); CVT8ADD(q2); CVT8ADD(q3);
            CVT8ADD(q4); CVT8ADD(q5); CVT8ADD(q6); CVT8ADD(q7);
        }
        for (; j < end; j += 2) {
            int s = __builtin_nontemporal_load(csr + j);
            float4 qq = *(const float4*)(mh + (size_t)s * 32 + quarter * 8);
            CVT8ADD(qq);
        }
        b = batch[v];
    }
    RED8(4);   // fold edge-slot q
    float part = 0.f;
    if (valid) {
        float dv = dinv[v];
        float4 qs = *(const float4*)(mh + (size_t)v * 32 + quarter * 8);
        const __half2* sp = (const __half2*)&qs;
        float2 s0 = __half22float2(sp[0]), s1 = __half22float2(sp[1]);
        float2 s2 = __half22float2(sp[2]), s3 = __half22float2(sp[3]);
        const float* bb = b2 + quarter * 8;
        const float* wf = Wfc + quarter * 8;
        part  = fmaxf((a0 + s0.x) * dv + bb[0], 0.f) * wf[0];
        part += fmaxf((a1 + s0.y) * dv + bb[1], 0.f) * wf[1];
        part += fmaxf((a2 + s1.x) * dv + bb[2], 0.f) * wf[2];
        part += fmaxf((a3 + s1.y) * dv + bb[3], 0.f) * wf[3];
        part += fmaxf((a4 + s2.x) * dv + bb[4], 0.f) * wf[4];
        part += fmaxf((a5 + s2.y) * dv + bb[5], 0.f) * wf[5];
        part += fmaxf((a6 + s3.x) * dv + bb[6], 0.f) * wf[6];
        part += fmaxf((a7 + s3.y) * dv + bb[7], 0.f) * wf[7];
    }
    // fold quarters (masks 1,2): every lane of the node now holds t[v]
    part += __shfl_xor(part, 1);
    part += __shfl_xor(part, 2);
    int b0 = __shfl(b, 0);
    bool uni = __all(!valid || b == b0);
    if (uni) {
        // butterfly over node slots: lane 0's partner set {0,8,...,56} counts
        // each node's t exactly once.
        part += __shfl_xor(part, 8);
        part += __shfl_xor(part, 16);
        part += __shfl_xor(part, 32);
        if ((threadIdx.x & 63) == 0 && b0 >= 0) {
            atomicAdd(pooledS + b0, part);
        }
    } else if (valid && (threadIdx.x & 7) == 0) {
        atomicAdd(pooledS + b, part);
    }
    // ---- fused final FC: last block computes sigmoid over pooledS -----------
    __threadfence();
    __shared__ int lastFlag;
    if (threadIdx.x == 0) {
        int prev = atomicAdd(done, 1);
        lastFlag = (prev == (int)gridDim.x - 1) ? 1 : 0;
    }
    __syncthreads();
    if (lastFlag) {
        float bias = bfc[0];
        for (int g = threadIdx.x; g < N_GRAPHS; g += blockDim.x) {
            float pv = atomicAdd(pooledS + g, 0.0f);   // coherent device-scope read
            out[g] = 1.0f / (1.0f + expf(-(pv + bias)));
        }
    }
}

extern "C" void kernel_launch(void* const* d_in, const int* in_sizes, int n_in,
                              void* d_out, int out_size, void* d_ws, size_t ws_size,
                              hipStream_t stream) {
    const int n  = in_sizes[0] / 10;   // 100000 nodes
    const int ne = in_sizes[1] / 2;    // 1600000 edges
    const int nb = (n + 255) >> 8;     // 391 buckets

    const float* x     = (const float*)d_in[0];
    const int*   ei    = (const int*)d_in[1];
    const int*   batch = (const int*)d_in[2];
    const float* W1    = (const float*)d_in[3];
    const float* b1    = (const float*)d_in[4];
    const float* W2    = (const float*)d_in[5];
    const float* b2    = (const float*)d_in[6];
    const float* Wfc   = (const float*)d_in[7];
    const float* bfc   = (const float*)d_in[8];
    const int* srcp = ei;
    const int* dstp = ei + ne;

    // workspace layout
    char* base = (char*)d_ws;
    size_t off = 0;
    auto take = [&](size_t bytes) { void* p = base + off; off = align_up(off + bytes, 16); return p; };
    int*      cursor    = (int*)     take((size_t)nb * 4);
    int*      bucketBuf = (int*)     take((size_t)nb * CAP * 4);
    int*      csr       = (int*)     take((size_t)nb * CAP * 4);
    unsigned* pk        = (unsigned*)take((size_t)n * 4);
    float*    dinv      = (float*)   take((size_t)n * 4);
    __half*   xh        = (__half*)  take((size_t)n * 16 * 2);
    __half*   mh        = (__half*)  take((size_t)n * 32 * 2);   // [n][32]
    float*    pooledS   = (float*)   take((size_t)N_GRAPHS * 4);
    int*      done      = (int*)     take(16);

    k_init   <<<4, 256, 0, stream>>>(cursor, pooledS, done, nb);
    k_bucketA<<<(ne + TILE_A - 1) / TILE_A, 256, 0, stream>>>(srcp, dstp, cursor, bucketBuf, ne, nb);
    k_bucketB<<<nb, 256, 0, stream>>>(cursor, bucketBuf, x, csr, pk, dinv, xh, n);
    k_g1lin  <<<(n + 63) / 64, 512, 0, stream>>>(csr, pk, dinv, xh, W1, b1, W2, mh, n);
    k_gath2  <<<(n + 31) / 32, 256, 0, stream>>>(csr, pk, dinv, mh, b2, Wfc, batch,
                                                 pooledS, done, bfc, (float*)d_out, n);
}

// Round 17
// 120.971 us; speedup vs baseline: 3.4535x; 3.4535x over previous
//
#include <hip/hip_runtime.h>
#include <hip/hip_fp16.h>
#include <math.h>

#define N_GRAPHS 512
#define CAP 5120          // bucket capacity: mean 4096, sigma 64
#define TILE_A 4096       // edges per phase-A workgroup (16/thread)

static inline size_t align_up(size_t v, size_t a) { return (v + a - 1) / a * a; }

// ---- init: bucket cursors + zero scalar pooled ------------------------------
__global__ void k_init(int* __restrict__ cursor, float* __restrict__ pooledS, int nb) {
    int i = blockIdx.x * blockDim.x + threadIdx.x;
    if (i < nb) cursor[i] = i * CAP;
    if (i < N_GRAPHS) pooledS[i] = 0.f;
}

// ---- Phase A: partition edges into dst-range buckets ------------------------
__global__ void k_bucketA(const int* __restrict__ src, const int* __restrict__ dst,
                          int* __restrict__ cursor, int* __restrict__ bucketBuf,
                          int ne, int nb) {
    __shared__ int hist[512];
    __shared__ int base[512];
    for (int i = threadIdx.x; i < nb; i += 256) hist[i] = 0;
    __syncthreads();
    int t0 = blockIdx.x * TILE_A + threadIdx.x;
    int s[16], d[16];
#pragma unroll
    for (int k = 0; k < 16; ++k) {
        int e = t0 + k * 256;
        if (e < ne) {
            s[k] = __builtin_nontemporal_load(src + e);
            d[k] = __builtin_nontemporal_load(dst + e);
        } else { s[k] = 0; d[k] = -1; }
    }
#pragma unroll
    for (int k = 0; k < 16; ++k)
        if (d[k] >= 0) atomicAdd(&hist[d[k] >> 8], 1);
    __syncthreads();
    for (int i = threadIdx.x; i < nb; i += 256)
        base[i] = (hist[i] > 0) ? atomicAdd(&cursor[i], hist[i]) : 0;
    __syncthreads();
#pragma unroll
    for (int k = 0; k < 16; ++k)
        if (d[k] >= 0) {
            int b = d[k] >> 8;
            int slot = atomicAdd(&base[b], 1);
            int lim = b * CAP + (CAP - 1);
            if (slot > lim) slot = lim;   // overflow guard (never expected)
            bucketBuf[slot] = (s[k] << 8) | (d[k] & 255);
        }
}

// ---- Phase B: counting sort -> csr + pk + dinv + prescaled fp16 x [n][16] ---
__global__ void k_bucketB(const int* __restrict__ cursor, const int* __restrict__ bucketBuf,
                          const float* __restrict__ x,
                          int* __restrict__ csr, unsigned* __restrict__ pk,
                          float* __restrict__ dinv, __half* __restrict__ xh, int n) {
    int b = blockIdx.x;
    int beg = b * CAP;
    int cnt = cursor[b] - beg;
    if (cnt > CAP) cnt = CAP;
    __shared__ int hist[256];
    __shared__ int scan[256];
    hist[threadIdx.x] = 0;
    __syncthreads();
    for (int j = threadIdx.x; j < cnt; j += 256)
        atomicAdd(&hist[__builtin_nontemporal_load(bucketBuf + beg + j) & 255], 1);
    __syncthreads();
    int v = hist[threadIdx.x];
    scan[threadIdx.x] = v;
    __syncthreads();
    for (int off = 1; off < 256; off <<= 1) {
        int t = (threadIdx.x >= off) ? scan[threadIdx.x - off] : 0;
        __syncthreads();
        scan[threadIdx.x] += t;
        __syncthreads();
    }
    int excl = scan[threadIdx.x] - v;
    int node = (b << 8) + threadIdx.x;
    if (node < n) {
        pk[node] = (unsigned)(beg + excl) | ((unsigned)v << 22);
        float dd = (float)v + 1.0f;
        float dv = 1.0f / sqrtf(dd);
        dinv[node] = dv;
        // fused pad: xh[node] = dv * x[node], 10 feats zero-padded to 16 (fp16)
        const float* row = x + (size_t)node * 10;
        float vals[16];
#pragma unroll
        for (int k = 0; k < 10; ++k) vals[k] = row[k] * dv;
#pragma unroll
        for (int k = 10; k < 16; ++k) vals[k] = 0.f;
        __half2 out[8];
#pragma unroll
        for (int i = 0; i < 8; ++i) out[i] = __floats2half2_rn(vals[2 * i], vals[2 * i + 1]);
        *(float4*)(xh + (size_t)node * 16)     = *(float4*)(out);
        *(float4*)(xh + (size_t)node * 16 + 8) = *(float4*)(out + 4);
    }
    __syncthreads();
    hist[threadIdx.x] = excl;   // reuse as scatter cursor
    __syncthreads();
    for (int j = threadIdx.x; j < cnt; j += 256) {
        int pkk = __builtin_nontemporal_load(bucketBuf + beg + j);
        int slot = atomicAdd(&hist[pkk & 255], 1);
        csr[beg + slot] = pkk >> 8;
    }
}

// 8 fp16 feats -> add into a0..a7
#define CVT8ADD(qq) do { \
    const __half2* hp_ = (const __half2*)&(qq); \
    float2 f0_ = __half22float2(hp_[0]); \
    float2 f1_ = __half22float2(hp_[1]); \
    float2 f2_ = __half22float2(hp_[2]); \
    float2 f3_ = __half22float2(hp_[3]); \
    a0 += f0_.x; a1 += f0_.y; a2 += f1_.x; a3 += f1_.y; \
    a4 += f2_.x; a5 += f2_.y; a6 += f3_.x; a7 += f3_.y; } while (0)

#define RED8(mask) do { \
    a0 += __shfl_xor(a0, mask); a1 += __shfl_xor(a1, mask); \
    a2 += __shfl_xor(a2, mask); a3 += __shfl_xor(a3, mask); \
    a4 += __shfl_xor(a4, mask); a5 += __shfl_xor(a5, mask); \
    a6 += __shfl_xor(a6, mask); a7 += __shfl_xor(a7, mask); } while (0)

// 4-edge-unrolled gather loop over a table of 32 B fp16 rows
// lane layout: half = lane&1; edge-slot q = (lane>>1)&3; node slot = lane>>3
#define GATHER_LOOP16(tbl) do { \
    int j = beg + q; \
    for (; j + 12 < end; j += 16) { \
        int sA = __builtin_nontemporal_load(csr + j); \
        int sB = __builtin_nontemporal_load(csr + j + 4); \
        int sC = __builtin_nontemporal_load(csr + j + 8); \
        int sD = __builtin_nontemporal_load(csr + j + 12); \
        float4 qA = *(const float4*)((tbl) + (size_t)sA * 16 + half * 8); \
        float4 qB = *(const float4*)((tbl) + (size_t)sB * 16 + half * 8); \
        float4 qC = *(const float4*)((tbl) + (size_t)sC * 16 + half * 8); \
        float4 qD = *(const float4*)((tbl) + (size_t)sD * 16 + half * 8); \
        CVT8ADD(qA); CVT8ADD(qB); CVT8ADD(qC); CVT8ADD(qD); \
    } \
    for (; j < end; j += 4) { \
        int s = __builtin_nontemporal_load(csr + j); \
        float4 qq = *(const float4*)((tbl) + (size_t)s * 16 + half * 8); \
        CVT8ADD(qq); \
    } } while (0)

// ---- fused gather1 + MLP: mh = fp16(dinv * (relu(z@W1+b1)@W2))  [n][32] -----
// 64 nodes per 512-thread block; z only in LDS; x table fp16 [n][16] (3.2 MB).
__global__ void k_g1lin(const int* __restrict__ csr, const unsigned* __restrict__ pk,
                        const float* __restrict__ dinv, const __half* __restrict__ xh,
                        const float* __restrict__ W1, const float* __restrict__ b1,
                        const float* __restrict__ W2, __half* __restrict__ mh, int n) {
    __shared__ __align__(16) float W1s[640];
    __shared__ __align__(16) float W2s[2048];
    __shared__ __align__(16) float zt[64 * 17];
    __shared__ __align__(16) float hs[64 * 65];
    for (int i = threadIdx.x; i < 640; i += 512)  W1s[i] = W1[i];
    for (int i = threadIdx.x; i < 2048; i += 512) W2s[i] = W2[i];

    int half = threadIdx.x & 1;
    int q = (threadIdx.x >> 1) & 3;
    int slot = threadIdx.x >> 3;                 // 0..63
    int v = blockIdx.x * 64 + slot;
    bool valid = (v < n);
    float a0=0.f,a1=0.f,a2=0.f,a3=0.f,a4=0.f,a5=0.f,a6=0.f,a7=0.f;
    if (valid) {
        unsigned p = pk[v];
        int beg = (int)(p & 0x3FFFFFu), end = beg + (int)(p >> 22);
        GATHER_LOOP16(xh);
    }
    RED8(2); RED8(4);
    if (q == 0) {
        float o[8] = {0.f,0.f,0.f,0.f,0.f,0.f,0.f,0.f};
        if (valid) {
            float dv = dinv[v];
            float4 qs = *(const float4*)(xh + (size_t)v * 16 + half * 8);
            const __half2* sp = (const __half2*)&qs;
            float2 s0 = __half22float2(sp[0]), s1 = __half22float2(sp[1]);
            float2 s2 = __half22float2(sp[2]), s3 = __half22float2(sp[3]);
            o[0] = (a0 + s0.x) * dv; o[1] = (a1 + s0.y) * dv;
            o[2] = (a2 + s1.x) * dv; o[3] = (a3 + s1.y) * dv;
            o[4] = (a4 + s2.x) * dv; o[5] = (a5 + s2.y) * dv;
            o[6] = (a6 + s3.x) * dv; o[7] = (a7 + s3.y) * dv;
        }
        float* zr = zt + slot * 17 + half * 8;
#pragma unroll
        for (int i = 0; i < 8; ++i) zr[i] = o[i];
    }
    __syncthreads();
    // h1 phase: node = tid&63, w = tid>>6 computes 8 consecutive feats via
    // broadcast b128 W1 reads (all 64 lanes same address).
    {
        int node = threadIdx.x & 63, w = threadIdx.x >> 6;
        float zreg[10];
#pragma unroll
        for (int k = 0; k < 10; ++k) zreg[k] = zt[node * 17 + k];
        float acc[8];
        {
            float4 bva = *(const float4*)(b1 + w * 8);
            float4 bvb = *(const float4*)(b1 + w * 8 + 4);
            acc[0] = bva.x; acc[1] = bva.y; acc[2] = bva.z; acc[3] = bva.w;
            acc[4] = bvb.x; acc[5] = bvb.y; acc[6] = bvb.z; acc[7] = bvb.w;
        }
        const float4* W1v = (const float4*)W1s;
#pragma unroll
        for (int k = 0; k < 10; ++k) {
            float zk = zreg[k];
            float4 wa = W1v[k * 16 + w * 2];
            float4 wb = W1v[k * 16 + w * 2 + 1];
            acc[0] += zk * wa.x; acc[1] += zk * wa.y;
            acc[2] += zk * wa.z; acc[3] += zk * wa.w;
            acc[4] += zk * wb.x; acc[5] += zk * wb.y;
            acc[6] += zk * wb.z; acc[7] += zk * wb.w;
        }
        float* hr = hs + node * 65 + w * 8;
#pragma unroll
        for (int i = 0; i < 8; ++i) hr[i] = fmaxf(acc[i], 0.f);
    }
    __syncthreads();
    // m phase (register-blocked): node = tid>>3, 4 consecutive outputs og*4..+3.
    {
        int node = threadIdx.x >> 3, og = threadIdx.x & 7;
        int vv = blockIdx.x * 64 + node;
        if (vv < n) {
            float s0 = 0.f, s1 = 0.f, s2 = 0.f, s3 = 0.f;
            const float4* W2v = (const float4*)W2s;   // [f][32] -> f*8 float4s
            const float* hr = hs + node * 65;
#pragma unroll
            for (int f = 0; f < 64; ++f) {
                float hv = hr[f];
                float4 w4 = W2v[f * 8 + og];
                s0 += hv * w4.x; s1 += hv * w4.y;
                s2 += hv * w4.z; s3 += hv * w4.w;
            }
            float dv = dinv[vv];
            __half2 p0 = __floats2half2_rn(s0 * dv, s1 * dv);
            __half2 p1 = __floats2half2_rn(s2 * dv, s3 * dv);
            __half2* outp = (__half2*)(mh + (size_t)vv * 32 + og * 4);
            outp[0] = p0; outp[1] = p1;
        }
    }
}

// ---- gather2 single pass (32 fp16 feats, 64 B rows) + relu + FC + pool ------
// lane layout: quarter = lane&3; edge-slot q = (lane>>2)&1; node slot = lane>>3
__global__ void k_gath2(const int* __restrict__ csr, const unsigned* __restrict__ pk,
                        const float* __restrict__ dinv, const __half* __restrict__ mh,
                        const float* __restrict__ b2, const float* __restrict__ Wfc,
                        const int* __restrict__ batch, float* __restrict__ pooledS, int n) {
    int quarter = threadIdx.x & 3;
    int q = (threadIdx.x >> 2) & 1;
    int v = blockIdx.x * 32 + (threadIdx.x >> 3);
    bool valid = (v < n);
    float a0=0.f,a1=0.f,a2=0.f,a3=0.f,a4=0.f,a5=0.f,a6=0.f,a7=0.f;
    int b = -1;
    if (valid) {
        unsigned p = pk[v];
        int beg = (int)(p & 0x3FFFFFu), end = beg + (int)(p >> 22);
        int j = beg + q;
        for (; j + 6 < end; j += 8) {
            int sA = __builtin_nontemporal_load(csr + j);
            int sB = __builtin_nontemporal_load(csr + j + 2);
            int sC = __builtin_nontemporal_load(csr + j + 4);
            int sD = __builtin_nontemporal_load(csr + j + 6);
            float4 qA = *(const float4*)(mh + (size_t)sA * 32 + quarter * 8);
            float4 qB = *(const float4*)(mh + (size_t)sB * 32 + quarter * 8);
            float4 qC = *(const float4*)(mh + (size_t)sC * 32 + quarter * 8);
            float4 qD = *(const float4*)(mh + (size_t)sD * 32 + quarter * 8);
            CVT8ADD(qA); CVT8ADD(qB); CVT8ADD(qC); CVT8ADD(qD);
        }
        for (; j < end; j += 2) {
            int s = __builtin_nontemporal_load(csr + j);
            float4 qq = *(const float4*)(mh + (size_t)s * 32 + quarter * 8);
            CVT8ADD(qq);
        }
        b = batch[v];
    }
    RED8(4);   // fold edge-slot q
    float part = 0.f;
    if (valid) {
        float dv = dinv[v];
        float4 qs = *(const float4*)(mh + (size_t)v * 32 + quarter * 8);
        const __half2* sp = (const __half2*)&qs;
        float2 s0 = __half22float2(sp[0]), s1 = __half22float2(sp[1]);
        float2 s2 = __half22float2(sp[2]), s3 = __half22float2(sp[3]);
        const float* bb = b2 + quarter * 8;
        const float* wf = Wfc + quarter * 8;
        part  = fmaxf((a0 + s0.x) * dv + bb[0], 0.f) * wf[0];
        part += fmaxf((a1 + s0.y) * dv + bb[1], 0.f) * wf[1];
        part += fmaxf((a2 + s1.x) * dv + bb[2], 0.f) * wf[2];
        part += fmaxf((a3 + s1.y) * dv + bb[3], 0.f) * wf[3];
        part += fmaxf((a4 + s2.x) * dv + bb[4], 0.f) * wf[4];
        part += fmaxf((a5 + s2.y) * dv + bb[5], 0.f) * wf[5];
        part += fmaxf((a6 + s3.x) * dv + bb[6], 0.f) * wf[6];
        part += fmaxf((a7 + s3.y) * dv + bb[7], 0.f) * wf[7];
    }
    // fold quarters (masks 1,2): every lane of the node now holds t[v]
    part += __shfl_xor(part, 1);
    part += __shfl_xor(part, 2);
    int b0 = __shfl(b, 0);
    bool uni = __all(!valid || b == b0);
    if (uni) {
        // butterfly over node slots: lane 0's partner set {0,8,...,56} counts
        // each node's t exactly once.
        part += __shfl_xor(part, 8);
        part += __shfl_xor(part, 16);
        part += __shfl_xor(part, 32);
        if ((threadIdx.x & 63) == 0 && b0 >= 0) {
            atomicAdd(pooledS + b0, part);
        }
    } else if (valid && (threadIdx.x & 7) == 0) {
        atomicAdd(pooledS + b, part);
    }
}

// ---- out[g] = sigmoid(pooledS[g] + bfc) -------------------------------------
__global__ void k_fc(const float* __restrict__ pooledS, const float* __restrict__ bfc,
                     float* __restrict__ out) {
    int g = blockIdx.x * blockDim.x + threadIdx.x;
    if (g < N_GRAPHS) out[g] = 1.0f / (1.0f + expf(-(pooledS[g] + bfc[0])));
}

extern "C" void kernel_launch(void* const* d_in, const int* in_sizes, int n_in,
                              void* d_out, int out_size, void* d_ws, size_t ws_size,
                              hipStream_t stream) {
    const int n  = in_sizes[0] / 10;   // 100000 nodes
    const int ne = in_sizes[1] / 2;    // 1600000 edges
    const int nb = (n + 255) >> 8;     // 391 buckets

    const float* x     = (const float*)d_in[0];
    const int*   ei    = (const int*)d_in[1];
    const int*   batch = (const int*)d_in[2];
    const float* W1    = (const float*)d_in[3];
    const float* b1    = (const float*)d_in[4];
    const float* W2    = (const float*)d_in[5];
    const float* b2    = (const float*)d_in[6];
    const float* Wfc   = (const float*)d_in[7];
    const float* bfc   = (const float*)d_in[8];
    const int* srcp = ei;
    const int* dstp = ei + ne;

    // workspace layout
    char* base = (char*)d_ws;
    size_t off = 0;
    auto take = [&](size_t bytes) { void* p = base + off; off = align_up(off + bytes, 16); return p; };
    int*      cursor    = (int*)     take((size_t)nb * 4);
    int*      bucketBuf = (int*)     take((size_t)nb * CAP * 4);
    int*      csr       = (int*)     take((size_t)nb * CAP * 4);
    unsigned* pk        = (unsigned*)take((size_t)n * 4);
    float*    dinv      = (float*)   take((size_t)n * 4);
    __half*   xh        = (__half*)  take((size_t)n * 16 * 2);
    __half*   mh        = (__half*)  take((size_t)n * 32 * 2);   // [n][32]
    float*    pooledS   = (float*)   take((size_t)N_GRAPHS * 4);

    k_init   <<<4, 256, 0, stream>>>(cursor, pooledS, nb);
    k_bucketA<<<(ne + TILE_A - 1) / TILE_A, 256, 0, stream>>>(srcp, dstp, cursor, bucketBuf, ne, nb);
    k_bucketB<<<nb, 256, 0, stream>>>(cursor, bucketBuf, x, csr, pk, dinv, xh, n);
    k_g1lin  <<<(n + 63) / 64, 512, 0, stream>>>(csr, pk, dinv, xh, W1, b1, W2, mh, n);
    k_gath2  <<<(n + 31) / 32, 256, 0, stream>>>(csr, pk, dinv, mh,
                                                 b2, Wfc, batch, pooledS, n);
    k_fc     <<<2, 256, 0, stream>>>(pooledS, bfc, (float*)d_out);
}